// Round 4
// baseline (502.423 us; speedup 1.0000x reference)
//
#include <hip/hip_runtime.h>

// 12-bit ripple-borrow subtractor on binary spike inputs.
// diff = (packA - packB) & 0xFFF, borrow = packB > packA. Exact vs soft-gate
// algebra on {0,1} inputs.
//
// R4 == R3 with native ext_vector_type for nontemporal 16B stores
// (HIP_vector_type uint4 is a class; the builtin rejects it).
//   Persistent grid-stride waves + explicit register software pipeline:
//   next iteration's 6 loads issued before current iteration's compute+store.
//   Integer path: 1.0f == 0x3F800000 -> bit29 test; no float cvt needed.

#define TPB  256
#define NBLK 2048

typedef unsigned int uv4 __attribute__((ext_vector_type(4)));

__device__ __forceinline__ unsigned pack12(const uv4& w0, const uv4& w1, const uv4& w2) {
    // each word is 0x3F800000 (1.0f) or 0x00000000; bit 29 distinguishes.
    unsigned p;
    p  = ((w0.x >> 29) & 1u) << 11;
    p |= ((w0.y >> 29) & 1u) << 10;
    p |= ((w0.z >> 29) & 1u) << 9;
    p |= ((w0.w >> 29) & 1u) << 8;
    p |= ((w1.x >> 29) & 1u) << 7;
    p |= ((w1.y >> 29) & 1u) << 6;
    p |= ((w1.z >> 29) & 1u) << 5;
    p |= ((w1.w >> 29) & 1u) << 4;
    p |= ((w2.x >> 29) & 1u) << 3;
    p |= ((w2.y >> 29) & 1u) << 2;
    p |= ((w2.z >> 29) & 1u) << 1;
    p |= ((w2.w >> 29) & 1u);
    return p;
}

__device__ __forceinline__ unsigned bit2onef(unsigned diff, int k) {
    // ((diff>>k)&1) ? 0x3F800000 (1.0f) : 0
    return 0x3F800000u & (0u - ((diff >> k) & 1u));
}

__global__ __launch_bounds__(TPB) void Subtractor12Bit_kernel(
    const uv4* __restrict__ A4,   // [batch*3] uv4 == [batch][12] f32 bits
    const uv4* __restrict__ B4,
    uv4* __restrict__ D4,         // diffs
    float* __restrict__ Borrow,   // [batch]
    int batch)
{
    const int stride = gridDim.x * TPB;
    int row = blockIdx.x * TPB + threadIdx.x;
    if (row >= batch) return;

    uv4 a0, a1, a2, b0, b1, b2;
    {
        const size_t base = (size_t)row * 3;
        a0 = A4[base + 0]; a1 = A4[base + 1]; a2 = A4[base + 2];
        b0 = B4[base + 0]; b1 = B4[base + 1]; b2 = B4[base + 2];
    }

    while (true) {
        const int next = row + stride;
        const bool have_next = next < batch;

        // ---- prefetch next iteration's inputs (stay in flight across compute) ----
        uv4 na0, na1, na2, nb0, nb1, nb2;
        if (have_next) {
            const size_t nb = (size_t)next * 3;
            na0 = A4[nb + 0]; na1 = A4[nb + 1]; na2 = A4[nb + 2];
            nb0 = B4[nb + 0]; nb1 = B4[nb + 1]; nb2 = B4[nb + 2];
        }

        // ---- compute + store current ----
        const unsigned ua = pack12(a0, a1, a2);
        const unsigned ub = pack12(b0, b1, b2);
        const unsigned diff = (ua - ub) & 0xFFFu;

        uv4 d0 = {bit2onef(diff, 11), bit2onef(diff, 10), bit2onef(diff, 9), bit2onef(diff, 8)};
        uv4 d1 = {bit2onef(diff, 7),  bit2onef(diff, 6),  bit2onef(diff, 5), bit2onef(diff, 4)};
        uv4 d2 = {bit2onef(diff, 3),  bit2onef(diff, 2),  bit2onef(diff, 1), bit2onef(diff, 0)};

        const size_t base = (size_t)row * 3;
        __builtin_nontemporal_store(d0, &D4[base + 0]);
        __builtin_nontemporal_store(d1, &D4[base + 1]);
        __builtin_nontemporal_store(d2, &D4[base + 2]);
        __builtin_nontemporal_store((ub > ua) ? 1.0f : 0.0f, &Borrow[row]);

        if (!have_next) break;
        a0 = na0; a1 = na1; a2 = na2;
        b0 = nb0; b1 = nb1; b2 = nb2;
        row = next;
    }
}

extern "C" void kernel_launch(void* const* d_in, const int* in_sizes, int n_in,
                              void* d_out, int out_size, void* d_ws, size_t ws_size,
                              hipStream_t stream) {
    const uv4* A = (const uv4*)d_in[0];
    const uv4* B = (const uv4*)d_in[1];
    float* out = (float*)d_out;

    const int batch = in_sizes[0] / 12;             // 4,194,304
    uv4* diffs = (uv4*)out;                         // [batch*3]
    float* borrow = out + (size_t)batch * 12;       // [batch]

    int grid = (batch + TPB - 1) / TPB;
    if (grid > NBLK) grid = NBLK;                   // 8 rows/thread at full batch
    Subtractor12Bit_kernel<<<grid, TPB, 0, stream>>>(A, B, diffs, borrow, batch);
}

// Round 5
// 467.748 us; speedup vs baseline: 1.0741x; 1.0741x over previous
//
#include <hip/hip_runtime.h>

// 12-bit ripple-borrow subtractor on binary spike inputs.
// diff = (packA - packB) & 0xFFF, borrow = packB > packA. Exact vs soft-gate
// algebra on {0,1} inputs.
//
// R5: R4 with PLAIN cached stores (nontemporal removed — nt 16B stores caused
// partial-line RMW at the MC: WRITE_SIZE 213->277 MB, dur 152->206 us).
// Persistent grid-stride waves + register software pipeline: next iteration's
// 6 loads are in flight across current iteration's compute+store.
// Integer path: 1.0f == 0x3F800000 -> bit29 test; no float cvt.

#define TPB  256
#define NBLK 2048

typedef unsigned int uv4 __attribute__((ext_vector_type(4)));

__device__ __forceinline__ unsigned pack12(const uv4& w0, const uv4& w1, const uv4& w2) {
    // each word is 0x3F800000 (1.0f) or 0x00000000; bit 29 distinguishes.
    unsigned p;
    p  = ((w0.x >> 29) & 1u) << 11;
    p |= ((w0.y >> 29) & 1u) << 10;
    p |= ((w0.z >> 29) & 1u) << 9;
    p |= ((w0.w >> 29) & 1u) << 8;
    p |= ((w1.x >> 29) & 1u) << 7;
    p |= ((w1.y >> 29) & 1u) << 6;
    p |= ((w1.z >> 29) & 1u) << 5;
    p |= ((w1.w >> 29) & 1u) << 4;
    p |= ((w2.x >> 29) & 1u) << 3;
    p |= ((w2.y >> 29) & 1u) << 2;
    p |= ((w2.z >> 29) & 1u) << 1;
    p |= ((w2.w >> 29) & 1u);
    return p;
}

__device__ __forceinline__ unsigned bit2onef(unsigned diff, int k) {
    // ((diff>>k)&1) ? 0x3F800000 (1.0f) : 0
    return 0x3F800000u & (0u - ((diff >> k) & 1u));
}

__global__ __launch_bounds__(TPB) void Subtractor12Bit_kernel(
    const uv4* __restrict__ A4,   // [batch*3] uv4 == [batch][12] f32 bits
    const uv4* __restrict__ B4,
    uv4* __restrict__ D4,         // diffs
    float* __restrict__ Borrow,   // [batch]
    int batch)
{
    const int stride = gridDim.x * TPB;
    int row = blockIdx.x * TPB + threadIdx.x;
    if (row >= batch) return;

    uv4 a0, a1, a2, b0, b1, b2;
    {
        const size_t base = (size_t)row * 3;
        a0 = A4[base + 0]; a1 = A4[base + 1]; a2 = A4[base + 2];
        b0 = B4[base + 0]; b1 = B4[base + 1]; b2 = B4[base + 2];
    }

    while (true) {
        const int next = row + stride;
        const bool have_next = next < batch;

        // ---- prefetch next iteration's inputs (stay in flight across compute) ----
        uv4 na0, na1, na2, nb0, nb1, nb2;
        if (have_next) {
            const size_t nb = (size_t)next * 3;
            na0 = A4[nb + 0]; na1 = A4[nb + 1]; na2 = A4[nb + 2];
            nb0 = B4[nb + 0]; nb1 = B4[nb + 1]; nb2 = B4[nb + 2];
        }

        // ---- compute + store current ----
        const unsigned ua = pack12(a0, a1, a2);
        const unsigned ub = pack12(b0, b1, b2);
        const unsigned diff = (ua - ub) & 0xFFFu;

        const size_t base = (size_t)row * 3;
        uv4 d0 = {bit2onef(diff, 11), bit2onef(diff, 10), bit2onef(diff, 9), bit2onef(diff, 8)};
        uv4 d1 = {bit2onef(diff, 7),  bit2onef(diff, 6),  bit2onef(diff, 5), bit2onef(diff, 4)};
        uv4 d2 = {bit2onef(diff, 3),  bit2onef(diff, 2),  bit2onef(diff, 1), bit2onef(diff, 0)};
        D4[base + 0] = d0;
        D4[base + 1] = d1;
        D4[base + 2] = d2;
        Borrow[row] = (ub > ua) ? 1.0f : 0.0f;

        if (!have_next) break;
        a0 = na0; a1 = na1; a2 = na2;
        b0 = nb0; b1 = nb1; b2 = nb2;
        row = next;
    }
}

extern "C" void kernel_launch(void* const* d_in, const int* in_sizes, int n_in,
                              void* d_out, int out_size, void* d_ws, size_t ws_size,
                              hipStream_t stream) {
    const uv4* A = (const uv4*)d_in[0];
    const uv4* B = (const uv4*)d_in[1];
    float* out = (float*)d_out;

    const int batch = in_sizes[0] / 12;             // 4,194,304
    uv4* diffs = (uv4*)out;                         // [batch*3]
    float* borrow = out + (size_t)batch * 12;       // [batch]

    int grid = (batch + TPB - 1) / TPB;
    if (grid > NBLK) grid = NBLK;                   // 8 rows/thread at full batch
    Subtractor12Bit_kernel<<<grid, TPB, 0, stream>>>(A, B, diffs, borrow, batch);
}

// Round 6
// 462.571 us; speedup vs baseline: 1.0862x; 1.0112x over previous
//
#include <hip/hip_runtime.h>

// 12-bit ripple-borrow subtractor on binary spike inputs.
// diff = (packA - packB) & 0xFFF, borrow = packB > packA. Exact vs soft-gate
// algebra on {0,1} inputs.
//
// R6: burst-length experiment. Theory: per-CU vmem queue is full and
// throughput = depth/latency; the A/B streams are channel/bank-aliased
// (201 MB apart ~ 0 mod interleave), so alternating A/B 1KB bursts ping-pong
// DRAM row buffers. 4 rows/thread with all A-loads issued as one 12-instr
// burst, then all B-loads, amortizes row thrash 4x -> lower latency -> more BW.
// Lanes stay coalesced (chunks strided by TPB within the block's 1024 rows).

#define TPB 256
#define RPT 4                      // rows per thread

typedef unsigned int uv4 __attribute__((ext_vector_type(4)));

__device__ __forceinline__ unsigned pack12(const uv4& w0, const uv4& w1, const uv4& w2) {
    // each word is 0x3F800000 (1.0f) or 0x00000000; bit 29 distinguishes.
    unsigned p;
    p  = ((w0.x >> 29) & 1u) << 11;
    p |= ((w0.y >> 29) & 1u) << 10;
    p |= ((w0.z >> 29) & 1u) << 9;
    p |= ((w0.w >> 29) & 1u) << 8;
    p |= ((w1.x >> 29) & 1u) << 7;
    p |= ((w1.y >> 29) & 1u) << 6;
    p |= ((w1.z >> 29) & 1u) << 5;
    p |= ((w1.w >> 29) & 1u) << 4;
    p |= ((w2.x >> 29) & 1u) << 3;
    p |= ((w2.y >> 29) & 1u) << 2;
    p |= ((w2.z >> 29) & 1u) << 1;
    p |= ((w2.w >> 29) & 1u);
    return p;
}

__device__ __forceinline__ unsigned bit2onef(unsigned diff, int k) {
    // ((diff>>k)&1) ? 0x3F800000 (1.0f) : 0
    return 0x3F800000u & (0u - ((diff >> k) & 1u));
}

__global__ __launch_bounds__(TPB) void Subtractor12Bit_kernel(
    const uv4* __restrict__ A4,   // [batch*3] uv4 == [batch][12] f32 bits
    const uv4* __restrict__ B4,
    uv4* __restrict__ D4,         // diffs
    float* __restrict__ Borrow,   // [batch]
    int batch)
{
    const int t = threadIdx.x;
    const int row0 = blockIdx.x * (TPB * RPT) + t;   // thread's rows: row0 + k*TPB

    uv4 a[RPT][3], b[RPT][3];

    // ---- A burst: 12 back-to-back dwordx4 loads ----
    #pragma unroll
    for (int k = 0; k < RPT; ++k) {
        const int r = row0 + k * TPB;
        if (r < batch) {
            const size_t base = (size_t)r * 3;
            a[k][0] = A4[base + 0];
            a[k][1] = A4[base + 1];
            a[k][2] = A4[base + 2];
        }
    }
    // ---- B burst: 12 back-to-back dwordx4 loads ----
    #pragma unroll
    for (int k = 0; k < RPT; ++k) {
        const int r = row0 + k * TPB;
        if (r < batch) {
            const size_t base = (size_t)r * 3;
            b[k][0] = B4[base + 0];
            b[k][1] = B4[base + 1];
            b[k][2] = B4[base + 2];
        }
    }

    // ---- compute + store ----
    #pragma unroll
    for (int k = 0; k < RPT; ++k) {
        const int r = row0 + k * TPB;
        if (r < batch) {
            const unsigned ua = pack12(a[k][0], a[k][1], a[k][2]);
            const unsigned ub = pack12(b[k][0], b[k][1], b[k][2]);
            const unsigned diff = (ua - ub) & 0xFFFu;

            const size_t base = (size_t)r * 3;
            uv4 d0 = {bit2onef(diff, 11), bit2onef(diff, 10), bit2onef(diff, 9), bit2onef(diff, 8)};
            uv4 d1 = {bit2onef(diff, 7),  bit2onef(diff, 6),  bit2onef(diff, 5), bit2onef(diff, 4)};
            uv4 d2 = {bit2onef(diff, 3),  bit2onef(diff, 2),  bit2onef(diff, 1), bit2onef(diff, 0)};
            D4[base + 0] = d0;
            D4[base + 1] = d1;
            D4[base + 2] = d2;
            Borrow[r] = (ub > ua) ? 1.0f : 0.0f;
        }
    }
}

extern "C" void kernel_launch(void* const* d_in, const int* in_sizes, int n_in,
                              void* d_out, int out_size, void* d_ws, size_t ws_size,
                              hipStream_t stream) {
    const uv4* A = (const uv4*)d_in[0];
    const uv4* B = (const uv4*)d_in[1];
    float* out = (float*)d_out;

    const int batch = in_sizes[0] / 12;                 // 4,194,304
    uv4* diffs = (uv4*)out;                             // [batch*3]
    float* borrow = out + (size_t)batch * 12;           // [batch]

    const int rowsPerBlock = TPB * RPT;                 // 1024
    const int grid = (batch + rowsPerBlock - 1) / rowsPerBlock;  // 4096
    Subtractor12Bit_kernel<<<grid, TPB, 0, stream>>>(A, B, diffs, borrow, batch);
}